// Round 8
// baseline (361.121 us; speedup 1.0000x reference)
//
#include <hip/hip_runtime.h>
#include <math.h>

#define D 128
#define LSTRIDE 136   // LDS row stride in halves

typedef _Float16 half8 __attribute__((ext_vector_type(8)));
typedef _Float16 half4v __attribute__((ext_vector_type(4)));
typedef float f32x4 __attribute__((ext_vector_type(4)));

// ============ fat1: edge count (non-returning atomics) + weight pre-pack ============

__global__ void k_fat1(const int* __restrict__ ei, int* __restrict__ counts,
                       int E, int countBlocks,
                       const float* __restrict__ convW, _Float16* __restrict__ Wf) {
    if ((int)blockIdx.x < countBlocks) {
        int e0 = (blockIdx.x * blockDim.x + threadIdx.x) * 4;
        if (e0 + 3 < E) {
            int4 d4 = *(const int4*)(ei + E + e0);
            atomicAdd(&counts[d4.x], 1);
            atomicAdd(&counts[d4.y], 1);
            atomicAdd(&counts[d4.z], 1);
            atomicAdd(&counts[d4.w], 1);
        } else {
            for (int e = e0; e < E; e++) atomicAdd(&counts[ei[E + e]], 1);
        }
    } else {
        // prepw: slot = (s*8+c)*64 + lane; elem j: k = s*32+(lane>>4)*8+j, n = c*16+(lane&15)
        const int bid = blockIdx.x - countBlocks;           // 0..31
        const int l = bid >> 3;                             // layer
        const int slot = (bid & 7) * 256 + threadIdx.x;
        const float* W = convW + (size_t)l * D * D;
        const int p = slot >> 6, ln = slot & 63;
        const int s = p >> 3, c = p & 7;
        const int kbase = s * 32 + ((ln >> 4) << 3);
        const int n = (c << 4) + (ln & 15);
        half8 hv;
#pragma unroll
        for (int j = 0; j < 8; j++) hv[j] = (_Float16)W[(size_t)(kbase + j) * D + n];
        *(half8*)(Wf + (size_t)l * D * D + (size_t)slot * 8) = hv;
    }
}

// scan over PADDED counts (ceil4) -> rowptrP (16B-aligned row starts);
// emits dinv = rsqrt(count+1) and a 64-bin degree histogram.
__global__ __launch_bounds__(256) void k_scan1(const int* __restrict__ counts,
                                               int* __restrict__ rowptrP,
                                               int* __restrict__ bsums,
                                               float* __restrict__ dinv,
                                               int* __restrict__ degHist, int N) {
    __shared__ int sh[256];
    __shared__ int lh[64];
    const int t = threadIdx.x;
    const int base = blockIdx.x * 1024 + t * 4;
    int c[4], pj[4];
#pragma unroll
    for (int j = 0; j < 4; j++) {
        c[j] = (base + j < N) ? counts[base + j] : 0;
        pj[j] = (c[j] + 3) & ~3;
    }
#pragma unroll
    for (int j = 0; j < 4; j++)
        if (base + j < N) dinv[base + j] = rsqrtf((float)(c[j] + 1));

    if (t < 64) lh[t] = 0;
    __syncthreads();
#pragma unroll
    for (int j = 0; j < 4; j++)
        if (base + j < N) atomicAdd(&lh[c[j] < 63 ? c[j] : 63], 1);
    __syncthreads();
    if (t < 64 && lh[t]) atomicAdd(&degHist[t], lh[t]);

    int tsum = pj[0] + pj[1] + pj[2] + pj[3];
    sh[t] = tsum;
    __syncthreads();
    for (int off = 1; off < 256; off <<= 1) {
        int v = (t >= off) ? sh[t - off] : 0;
        __syncthreads();
        sh[t] += v;
        __syncthreads();
    }
    int run = (t == 0) ? 0 : sh[t - 1];
    if (t == 255) bsums[blockIdx.x] = sh[255];
#pragma unroll
    for (int j = 0; j < 4; j++) {
        if (base + j <= N) rowptrP[base + j] = run;
        run += pj[j];
    }
}

// ============ fat2: scan3 (block prefix + sentinel pads + cursor copy) + counting-sort ============

__global__ __launch_bounds__(256) void k_fat2(int* __restrict__ rowptrP,
                                              const int* __restrict__ counts,
                                              const int* __restrict__ bsums,
                                              int NB, int N, int scanBlocks, int NS,
                                              int* __restrict__ srcs,
                                              int* __restrict__ cursor,
                                              const int* __restrict__ degHist,
                                              int* __restrict__ degCur,
                                              int* __restrict__ perm,
                                              int* __restrict__ rankOf) {
    if ((int)blockIdx.x < scanBlocks) {
        __shared__ int pre[128];
        const int t = threadIdx.x;
        if (t < 128) pre[t] = (t < NB) ? bsums[t] : 0;
        __syncthreads();
        for (int off = 1; off < 128; off <<= 1) {
            int v = (t >= off && t < 128) ? pre[t - off] : 0;
            __syncthreads();
            if (t < 128) pre[t] += v;
            __syncthreads();
        }
        int i = blockIdx.x * blockDim.x + t;
        if (i <= N) {
            int b = i >> 10;
            int add = (b == 0) ? 0 : pre[b - 1];
            int rp = rowptrP[i] + add;
            rowptrP[i] = rp;
            if (i < N) {
                cursor[i] = rp;                        // fill-time scatter cursor
                int c = counts[i];
                int re_ = rp + c;
                int pad = (-c) & 3;                    // 0..3 sentinel slots
                for (int k2 = 0; k2 < pad; k2++) srcs[re_ + k2] = NS;
            }
        }
    } else {
        // counting-sort rank assignment: perm (desc by degree) + rankOf
        __shared__ int lbase[64], lh[64], gb[64];
        const int t = threadIdx.x;
        const int i = ((int)blockIdx.x - scanBlocks) * blockDim.x + t;
        if (t < 64) lh[t] = 0;
        __syncthreads();
        int deg = 0, lrank = 0;
        const bool v = i < N;
        if (v) {
            int c = counts[i];
            deg = c < 63 ? c : 63;
            lrank = atomicAdd(&lh[deg], 1);
        }
        __syncthreads();
        if (t < 64) gb[t] = lh[t] ? atomicAdd(&degCur[t], lh[t]) : 0;
        if (t == 0) {
            int run = 0;
            for (int d = 63; d >= 0; d--) { lbase[d] = run; run += degHist[d]; }
        }
        __syncthreads();
        if (v) {
            int r = lbase[deg] + gb[deg] + lrank;
            perm[r] = i;
            rankOf[i] = r;
        }
    }
}

// ============ fill: edges (cursor atomics, rank-valued) + slot tables + cvt ============
// cvt reads x COALESCED in original order and writes gA as scattered FULL-LINE
// 256 B rows (no RMW, fire-and-forget) — replaces R6's scattered 256 B reads.

__global__ void k_fill(const int* __restrict__ ei, const int* __restrict__ rowptrP,
                       int* __restrict__ cursor, int* __restrict__ srcs, int E,
                       int fillBlocks, int tabBlocks, int N, int NS,
                       const int* __restrict__ rankOf,
                       const int* __restrict__ perm,
                       const float* __restrict__ dinv,
                       int* __restrict__ rbegR, int* __restrict__ rpenR,
                       float* __restrict__ dinvR, int* __restrict__ sentIdx,
                       const float* __restrict__ x,
                       _Float16* __restrict__ gA, _Float16* __restrict__ gB) {
    const int b = blockIdx.x;
    if (b < fillBlocks) {
        int e0 = (b * blockDim.x + threadIdx.x) * 4;
        if (e0 + 3 < E) {
            int4 s4 = *(const int4*)(ei + e0);
            int4 d4 = *(const int4*)(ei + E + e0);
            int p0 = atomicAdd(&cursor[d4.x], 1);
            int p1 = atomicAdd(&cursor[d4.y], 1);
            int p2 = atomicAdd(&cursor[d4.z], 1);
            int p3 = atomicAdd(&cursor[d4.w], 1);
            srcs[p0] = rankOf[s4.x];
            srcs[p1] = rankOf[s4.y];
            srcs[p2] = rankOf[s4.z];
            srcs[p3] = rankOf[s4.w];
        } else {
            for (int e = e0; e < E; e++)
                srcs[atomicAdd(&cursor[ei[E + e]], 1)] = rankOf[ei[e]];
        }
    } else if (b < fillBlocks + tabBlocks) {
        // rank-space slot tables
        const int r = (b - fillBlocks) * blockDim.x + threadIdx.x;
        if (r == 0) { int4 sv; sv.x = sv.y = sv.z = sv.w = NS; *(int4*)sentIdx = sv; }
        if (r < NS) {
            if (r < N) {
                int p = perm[r];
                rbegR[r] = rowptrP[p];
                rpenR[r] = rowptrP[p + 1];    // padded end (next padded start)
                dinvR[r] = dinv[p];
            } else {
                rbegR[r] = 0; rpenR[r] = 0; dinvR[r] = 0.f;
            }
        }
    } else {
        // cvt: original-order coalesced read, scattered full-row write to rank slot
        const int i = (b - fillBlocks - tabBlocks) * blockDim.x + threadIdx.x;
        const int TC = (NS + 1) * 16;
        if (i >= TC) return;
        const int row = i >> 4, j = i & 15;
        if (row < N) {
            const float s = dinv[row];
            const int rr = rankOf[row];
            const float4 v0 = *(const float4*)(x + (size_t)row * D + j * 8);
            const float4 v1 = *(const float4*)(x + (size_t)row * D + j * 8 + 4);
            half8 h;
            h[0] = (_Float16)(v0.x * s); h[1] = (_Float16)(v0.y * s);
            h[2] = (_Float16)(v0.z * s); h[3] = (_Float16)(v0.w * s);
            h[4] = (_Float16)(v1.x * s); h[5] = (_Float16)(v1.y * s);
            h[6] = (_Float16)(v1.z * s); h[7] = (_Float16)(v1.w * s);
            *(half8*)(gA + (size_t)rr * D + j * 8) = h;
        } else {
            half8 z;
#pragma unroll
            for (int j2 = 0; j2 < 8; j2++) z[j2] = (_Float16)0.f;
            *(half8*)(gA + (size_t)row * D + j * 8) = z;
            *(half8*)(gB + (size_t)row * D + j * 8) = z;
        }
    }
}

// ============ fused layer: gout = scale ⊙ relu( (dinv ⊙ Â g) @ W + b ) ============
// FROZEN at R6 structure (8 nodes/wave, 32/block, backfill occupancy ~60%):
// measured at the random-gather EA service wall (~2.7 TB/s, concurrency-
// insensitive per R3/R5/R6 A/B). Do not touch without a traffic-reduction idea.

__global__ __launch_bounds__(256, 8) void k_layer(
        const _Float16* __restrict__ gin,
        const int* __restrict__ rbegR, const int* __restrict__ rpenR,
        const int* __restrict__ srcs,
        const int* __restrict__ sentIdx,
        const float* __restrict__ dinvR,
        const int* __restrict__ perm,
        const _Float16* __restrict__ Wf,
        const float* __restrict__ bias,
        _Float16* __restrict__ gout, int N, int last) {
    __shared__ _Float16 S[32 * LSTRIDE];   // 8.7 KB

    const int tid  = threadIdx.x;
    const int w    = tid >> 6;        // wave 0..3
    const int lane = tid & 63;
    const int q    = lane >> 4;       // group 0..3
    const int l16  = lane & 15;       // lane-in-group; col base = l16*8
    const int sb   = blockIdx.x * 32; // slot base
    const int cb   = l16 * 8;
    const int slot0 = sb + w * 8 + q * 2;

    // ---- phase 1: branch-free interleaved gather over the group's 2 slots ----
    int bg[2], nc[2];
    int mx = 0;
#pragma unroll
    for (int it = 0; it < 2; it++) {
        bg[it] = rbegR[slot0 + it];
        nc[it] = (rpenR[slot0 + it] - bg[it]) >> 2;   // padded chunk count
        mx = nc[it] > mx ? nc[it] : mx;
    }

    float a[2][8];
#pragma unroll
    for (int it = 0; it < 2; it++) {                  // self-loop rows (coalesced)
        half8 sv = *(const half8*)(gin + (size_t)(slot0 + it) * D + cb);
#pragma unroll
        for (int j = 0; j < 8; j++) a[it][j] = (float)sv[j];
    }

    int4 cur[2];
#pragma unroll
    for (int it = 0; it < 2; it++) {
        const int* ip = (0 < nc[it]) ? (srcs + bg[it]) : sentIdx;
        cur[it] = *(const int4*)ip;
    }
    for (int ch = 0; ch < mx; ch++) {
        int4 nxt[2];
#pragma unroll
        for (int it = 0; it < 2; it++) {              // prefetch next chunk's indices
            const int* ip = (ch + 1 < nc[it]) ? (srcs + bg[it] + (ch + 1) * 4) : sentIdx;
            nxt[it] = *(const int4*)ip;
        }
#pragma unroll
        for (int it = 0; it < 2; it++) {              // 8 row loads in flight
            half8 v0 = *(const half8*)(gin + (size_t)cur[it].x * D + cb);
            half8 v1 = *(const half8*)(gin + (size_t)cur[it].y * D + cb);
            half8 v2 = *(const half8*)(gin + (size_t)cur[it].z * D + cb);
            half8 v3 = *(const half8*)(gin + (size_t)cur[it].w * D + cb);
#pragma unroll
            for (int j = 0; j < 8; j++)
                a[it][j] += ((float)v0[j] + (float)v1[j]) + ((float)v2[j] + (float)v3[j]);
        }
#pragma unroll
        for (int it = 0; it < 2; it++) cur[it] = nxt[it];
    }

#pragma unroll
    for (int it = 0; it < 2; it++) {
        const float sc = dinvR[slot0 + it];
        const int nl = w * 8 + q * 2 + it;
        half8 o;
#pragma unroll
        for (int j = 0; j < 8; j++) o[j] = (_Float16)(a[it][j] * sc);
        *(half8*)(&S[nl * LSTRIDE + cb]) = o;
    }

    __syncthreads();   // cross-wave: wave pair reads each other's S rows

    // ---- phase 2: S @ W via MFMA; wave pair splits the 8 cc's of one tile ----
    f32x4 acc[4];
#pragma unroll
    for (int c2 = 0; c2 < 4; c2++) acc[c2] = (f32x4){0.f, 0.f, 0.f, 0.f};

    const int tile = w >> 1;               // 0..1: which 16-node tile
    const int ccb  = (w & 1) * 4;          // this wave's cc range
    const int nl2  = tile * 16 + l16;      // this lane's slot row (B-frag)
#pragma unroll
    for (int s = 0; s < 4; s++) {
        half8 bf = *(const half8*)(&S[nl2 * LSTRIDE + s * 32 + q * 8]);
#pragma unroll
        for (int c2 = 0; c2 < 4; c2++) {
            half8 wh = *(const half8*)(Wf + (size_t)((s * 8 + ccb + c2) * 64 + lane) * 8);
            acc[c2] = __builtin_amdgcn_mfma_f32_16x16x32_f16(wh, bf, acc[c2], 0, 0, 0);
        }
    }

    // epilogue: D[m = W-col = q*4+r][n = slot = l16]
    const int slot2 = sb + nl2;
    if (!last) {
        const float scale = dinvR[slot2];             // 0 for dummy slots -> stays 0
        _Float16* rp = gout + (size_t)slot2 * D + q * 4;
#pragma unroll
        for (int c2 = 0; c2 < 4; c2++) {
            const int cc = ccb + c2;
            const float4 bc = *(const float4*)(bias + cc * 16 + q * 4);
            half4v o;
            o[0] = (_Float16)(fmaxf(acc[c2][0] + bc.x, 0.f) * scale);
            o[1] = (_Float16)(fmaxf(acc[c2][1] + bc.y, 0.f) * scale);
            o[2] = (_Float16)(fmaxf(acc[c2][2] + bc.z, 0.f) * scale);
            o[3] = (_Float16)(fmaxf(acc[c2][3] + bc.w, 0.f) * scale);
            *(half4v*)(rp + cc * 16) = o;   // 8 B store, coalesced rows
        }
    } else if (slot2 < N) {
        const int node2 = perm[slot2];                // back to original order
        _Float16* rp = gout + (size_t)node2 * D + q * 4;
#pragma unroll
        for (int c2 = 0; c2 < 4; c2++) {
            const int cc = ccb + c2;
            const float4 bc = *(const float4*)(bias + cc * 16 + q * 4);
            half4v o;
            o[0] = (_Float16)fmaxf(acc[c2][0] + bc.x, 0.f);
            o[1] = (_Float16)fmaxf(acc[c2][1] + bc.y, 0.f);
            o[2] = (_Float16)fmaxf(acc[c2][2] + bc.z, 0.f);
            o[3] = (_Float16)fmaxf(acc[c2][3] + bc.w, 0.f);
            *(half4v*)(rp + cc * 16) = o;
        }
    }
}

// ========== fused pool + MLP head: one block (256 thr) per graph ==========

__global__ __launch_bounds__(256) void k_poolhead(
        const _Float16* __restrict__ h, const int* __restrict__ batch,
        const float* __restrict__ W1, const float* __restrict__ b1,
        const float* __restrict__ W2, const float* __restrict__ b2,
        const float* __restrict__ W3, const float* __restrict__ b3,
        float* __restrict__ out, int N) {
    __shared__ int sb[2];
    __shared__ float part[16][D];
    __shared__ float pool[D];
    __shared__ float z[D];
    __shared__ float red[D];
    __shared__ float pr[2][D];

    const int g = blockIdx.x;
    const int t = threadIdx.x;

    if (t < 2) {
        int target = g + t;
        int lo = 0, hi = N;
        while (lo < hi) {
            int mid = (lo + hi) >> 1;
            if (batch[mid] < target) lo = mid + 1; else hi = mid;
        }
        sb[t] = lo;
    }
    __syncthreads();
    const int rs = sb[0], re = sb[1];

    const int w = t >> 6;
    const int lane = t & 63;
    const int rw = w * 4 + (lane >> 4);   // 0..15: row-slot within the 16-row stride
    const int c8 = (lane & 15) * 8;

    float ax[8];
#pragma unroll
    for (int j = 0; j < 8; j++) ax[j] = 0.f;
    for (int r = rs + rw; r < re; r += 16) {
        half8 vv = *(const half8*)(h + (size_t)r * D + c8);
#pragma unroll
        for (int j = 0; j < 8; j++) ax[j] += (float)vv[j];
    }
#pragma unroll
    for (int j = 0; j < 8; j++) part[rw][c8 + j] = ax[j];
    __syncthreads();

    if (t < D) {
        float s = 0.f;
#pragma unroll
        for (int gg = 0; gg < 16; gg++) s += part[gg][t];
        pool[t] = s;
    }
    __syncthreads();

    // matvec1: k-split across the two block halves, LDS combine
    {
        const int hf = t >> 7, tt = t & 127;
        const int k0 = hf * 64;
        float s = 0.f;
        for (int k = k0; k < k0 + 64; k++) s = fmaf(pool[k], W1[(size_t)k * D + tt], s);
        pr[hf][tt] = s;
    }
    __syncthreads();
    if (t < D) z[t] = fmaxf(pr[0][t] + pr[1][t] + b1[t], 0.f);
    __syncthreads();

    // matvec2: same split
    {
        const int hf = t >> 7, tt = t & 127;
        const int k0 = hf * 64;
        float s = 0.f;
        for (int k = k0; k < k0 + 64; k++) s = fmaf(z[k], W2[(size_t)k * D + tt], s);
        pr[hf][tt] = s;
    }
    __syncthreads();
    if (t < D) red[t] = fmaxf(pr[0][t] + pr[1][t] + b2[t], 0.f) * W3[t];
    __syncthreads();
    for (int off = 64; off >= 1; off >>= 1) {
        if (t < off) red[t] += red[t + off];
        __syncthreads();
    }
    if (t == 0) out[g] = 1.f / (1.f + expf(-(red[0] + b3[0])));
}

// ================= orchestration =================

extern "C" void kernel_launch(void* const* d_in, const int* in_sizes, int n_in,
                              void* d_out, int out_size, void* d_ws, size_t ws_size,
                              hipStream_t stream) {
    const float* x     = (const float*)d_in[0];
    const int*   ei    = (const int*)d_in[1];
    const int*   batch = (const int*)d_in[2];
    const float* convW = (const float*)d_in[3];
    const float* convB = (const float*)d_in[4];
    const float* W1 = (const float*)d_in[5];
    const float* b1 = (const float*)d_in[6];
    const float* W2 = (const float*)d_in[7];
    const float* b2 = (const float*)d_in[8];
    const float* W3 = (const float*)d_in[9];
    const float* b3 = (const float*)d_in[10];
    float* out = (float*)d_out;

    const int N = in_sizes[0] / D;          // 100000
    const int E = in_sizes[1] / 2;          // 640000
    const int G = out_size;                 // 512
    const int NB = (N + 1023) / 1024;
    const int NS = ((N + 63) / 64) * 64;    // slot count (64-aligned); sentinel row = NS

    // ---- workspace layout ----
    char* w = (char*)d_ws;
    size_t off = 0;
    auto alloc = [&](size_t bytes) -> char* {
        char* p = w + off;
        off += (bytes + 255) & ~(size_t)255;
        return p;
    };
    float*     dinv   = (float*)alloc((size_t)N * 4);
    _Float16*  gA     = (_Float16*)alloc((size_t)(NS + 1) * D * 2);
    _Float16*  gB     = (_Float16*)alloc((size_t)(NS + 1) * D * 2);
    _Float16*  Wf     = (_Float16*)alloc((size_t)4 * D * D * 2);
    int*       counts = (int*)alloc((size_t)(N + 128) * 4);  // + degHist[64] + degCur[64]
    int*       degHist= counts + N;
    int*       degCur = counts + N + 64;
    int*       rowptrP= (int*)alloc((size_t)(N + 1) * 4);
    int*       cursor = (int*)alloc((size_t)N * 4);
    int*       srcs   = (int*)alloc((size_t)(E + 3 * N) * 4);
    int*       bsums  = (int*)alloc((size_t)NB * 4);
    int*       perm   = (int*)alloc((size_t)N * 4);
    int*       rankOf = (int*)alloc((size_t)N * 4);
    int*       rbegR  = (int*)alloc((size_t)NS * 4);
    int*       rpenR  = (int*)alloc((size_t)NS * 4);
    float*     dinvR  = (float*)alloc((size_t)NS * 4);
    int*       sentIdx= (int*)alloc(16);

    // ---- CSR build + sort + rank-space tables + cvt ----
    hipMemsetAsync(counts, 0, (size_t)(N + 128) * 4, stream);
    const int countBlocks = (E / 4 + 255) / 256;
    k_fat1<<<countBlocks + 32, 256, 0, stream>>>(ei, counts, E, countBlocks,
                                                 convW, Wf);
    k_scan1<<<NB, 256, 0, stream>>>(counts, rowptrP, bsums, dinv, degHist, N);
    const int scanBlocks = (N + 1 + 255) / 256;
    const int rankBlocks = (N + 255) / 256;
    k_fat2<<<scanBlocks + rankBlocks, 256, 0, stream>>>(rowptrP, counts, bsums, NB, N,
                                                        scanBlocks, NS, srcs, cursor,
                                                        degHist, degCur, perm, rankOf);
    const int fillBlocks = (E / 4 + 255) / 256;
    const int tabBlocks  = (NS + 255) / 256;
    const int cvtBlocks  = ((NS + 1) * 16 + 255) / 256;
    k_fill<<<fillBlocks + tabBlocks + cvtBlocks, 256, 0, stream>>>(
        ei, rowptrP, cursor, srcs, E, fillBlocks, tabBlocks, N, NS,
        rankOf, perm, dinv, rbegR, rpenR, dinvR, sentIdx, x, gA, gB);

    // ---- 4 fused GCN layers (ping-pong, rank space; last scatters to orig) ----
    const int layer_grid = NS / 32;
    const _Float16* gi = gA;
    _Float16* go = gB;
    for (int l = 0; l < 4; l++) {
        k_layer<<<layer_grid, 256, 0, stream>>>(gi, rbegR, rpenR, srcs, sentIdx,
                                                dinvR, perm,
                                                Wf + (size_t)l * D * D,
                                                convB + (size_t)l * D,
                                                go, N, l == 3);
        const _Float16* tmp = go;
        go = (_Float16*)gi;
        gi = tmp;
    }

    // ---- fused pool + head ----
    k_poolhead<<<G, 256, 0, stream>>>(gi, batch, W1, b1, W2, b2, W3, b3, out, N);
}

// Round 9
// 343.639 us; speedup vs baseline: 1.0509x; 1.0509x over previous
//
#include <hip/hip_runtime.h>
#include <math.h>

#define D 128
#define LSTRIDE 136   // LDS row stride in halves

typedef _Float16 half8 __attribute__((ext_vector_type(8)));
typedef _Float16 half4v __attribute__((ext_vector_type(4)));
typedef float f32x4 __attribute__((ext_vector_type(4)));

// ============ fat1: edge count + within-bucket rank, plus weight pre-pack ============

__global__ void k_fat1(const int* __restrict__ ei, int* __restrict__ counts,
                       int* __restrict__ pidx, int E, int countBlocks,
                       const float* __restrict__ convW, _Float16* __restrict__ Wf) {
    if ((int)blockIdx.x < countBlocks) {
        int e0 = (blockIdx.x * blockDim.x + threadIdx.x) * 4;
        if (e0 + 3 < E) {
            int4 d4 = *(const int4*)(ei + E + e0);
            int4 p;
            p.x = atomicAdd(&counts[d4.x], 1);
            p.y = atomicAdd(&counts[d4.y], 1);
            p.z = atomicAdd(&counts[d4.z], 1);
            p.w = atomicAdd(&counts[d4.w], 1);
            *(int4*)(pidx + e0) = p;
        } else {
            for (int e = e0; e < E; e++) pidx[e] = atomicAdd(&counts[ei[E + e]], 1);
        }
    } else {
        // prepw: slot = (s*8+c)*64 + lane; elem j: k = s*32+(lane>>4)*8+j, n = c*16+(lane&15)
        const int bid = blockIdx.x - countBlocks;           // 0..31
        const int l = bid >> 3;                             // layer
        const int slot = (bid & 7) * 256 + threadIdx.x;
        const float* W = convW + (size_t)l * D * D;
        const int p = slot >> 6, ln = slot & 63;
        const int s = p >> 3, c = p & 7;
        const int kbase = s * 32 + ((ln >> 4) << 3);
        const int n = (c << 4) + (ln & 15);
        half8 hv;
#pragma unroll
        for (int j = 0; j < 8; j++) hv[j] = (_Float16)W[(size_t)(kbase + j) * D + n];
        *(half8*)(Wf + (size_t)l * D * D + (size_t)slot * 8) = hv;
    }
}

// scan over PADDED counts (ceil4) -> rowptrP (16B-aligned row starts);
// emits dinv = rsqrt(count+1) and a 64-bin degree histogram.
__global__ __launch_bounds__(256) void k_scan1(const int* __restrict__ counts,
                                               int* __restrict__ rowptrP,
                                               int* __restrict__ bsums,
                                               float* __restrict__ dinv,
                                               int* __restrict__ degHist, int N) {
    __shared__ int sh[256];
    __shared__ int lh[64];
    const int t = threadIdx.x;
    const int base = blockIdx.x * 1024 + t * 4;
    int c[4], pj[4];
#pragma unroll
    for (int j = 0; j < 4; j++) {
        c[j] = (base + j < N) ? counts[base + j] : 0;
        pj[j] = (c[j] + 3) & ~3;
    }
#pragma unroll
    for (int j = 0; j < 4; j++)
        if (base + j < N) dinv[base + j] = rsqrtf((float)(c[j] + 1));

    if (t < 64) lh[t] = 0;
    __syncthreads();
#pragma unroll
    for (int j = 0; j < 4; j++)
        if (base + j < N) atomicAdd(&lh[c[j] < 63 ? c[j] : 63], 1);
    __syncthreads();
    if (t < 64 && lh[t]) atomicAdd(&degHist[t], lh[t]);

    int tsum = pj[0] + pj[1] + pj[2] + pj[3];
    sh[t] = tsum;
    __syncthreads();
    for (int off = 1; off < 256; off <<= 1) {
        int v = (t >= off) ? sh[t - off] : 0;
        __syncthreads();
        sh[t] += v;
        __syncthreads();
    }
    int run = (t == 0) ? 0 : sh[t - 1];
    if (t == 255) bsums[blockIdx.x] = sh[255];
#pragma unroll
    for (int j = 0; j < 4; j++) {
        if (base + j <= N) rowptrP[base + j] = run;
        run += pj[j];
    }
}

// ============ fat2: scan3 (block prefix; NO pad writes — srcs pre-memset to 0,
// sentinel slot = 0) + counting-sort (ranks shifted to 1..N; slot 0 = zero row) ====

__global__ __launch_bounds__(256) void k_fat2(int* __restrict__ rowptrP,
                                              const int* __restrict__ counts,
                                              const int* __restrict__ bsums,
                                              int NB, int N, int scanBlocks,
                                              const int* __restrict__ degHist,
                                              int* __restrict__ degCur,
                                              int* __restrict__ perm,
                                              int* __restrict__ rankOf) {
    if ((int)blockIdx.x < scanBlocks) {
        __shared__ int pre[128];
        const int t = threadIdx.x;
        if (t < 128) pre[t] = (t < NB) ? bsums[t] : 0;
        __syncthreads();
        for (int off = 1; off < 128; off <<= 1) {
            int v = (t >= off && t < 128) ? pre[t - off] : 0;
            __syncthreads();
            if (t < 128) pre[t] += v;
            __syncthreads();
        }
        int i = blockIdx.x * blockDim.x + t;
        if (i <= N) {
            int b = i >> 10;
            int add = (b == 0) ? 0 : pre[b - 1];
            rowptrP[i] += add;
        }
    } else {
        // counting-sort rank assignment: slots 1..N desc by degree
        __shared__ int lbase[64], lh[64], gb[64];
        const int t = threadIdx.x;
        const int i = ((int)blockIdx.x - scanBlocks) * blockDim.x + t;
        if (t < 64) lh[t] = 0;
        __syncthreads();
        int deg = 0, lrank = 0;
        const bool v = i < N;
        if (v) {
            int c = counts[i];
            deg = c < 63 ? c : 63;
            lrank = atomicAdd(&lh[deg], 1);
        }
        __syncthreads();
        if (t < 64) gb[t] = lh[t] ? atomicAdd(&degCur[t], lh[t]) : 0;
        if (t == 0) {
            int run = 0;
            for (int d = 63; d >= 0; d--) { lbase[d] = run; run += degHist[d]; }
        }
        __syncthreads();
        if (v) {
            int r = 1 + lbase[deg] + gb[deg] + lrank;   // slots 1..N
            perm[r] = i;
            rankOf[i] = r;
        }
    }
}

// ============ fill: edges (slot-valued) + fused {slot tables + rank-space cvt} ============
// Section B: one block per 16 slots. perm/dinv loaded ONCE per slot into LDS;
// gA written coalesced in slot order; x read as row-aligned 256 B chunks.
// Slot 0 and slots >N are zero rows (in BOTH ping-pong buffers).

__global__ void k_fill(const int* __restrict__ ei, const int* __restrict__ rowptrP,
                       const int* __restrict__ pidx, int* __restrict__ srcs, int E,
                       int fillBlocks, int N, int NS,
                       const int* __restrict__ rankOf,
                       const int* __restrict__ perm,
                       const float* __restrict__ dinv,
                       int* __restrict__ rbegR, int* __restrict__ rpenR,
                       float* __restrict__ dinvR, int* __restrict__ sentIdx,
                       const float* __restrict__ x,
                       _Float16* __restrict__ gA, _Float16* __restrict__ gB) {
    const int b = blockIdx.x;
    if (b < fillBlocks) {
        int e0 = (b * blockDim.x + threadIdx.x) * 4;
        if (e0 + 3 < E) {
            int4 s4 = *(const int4*)(ei + e0);
            int4 d4 = *(const int4*)(ei + E + e0);
            int4 p4 = *(const int4*)(pidx + e0);
            srcs[rowptrP[d4.x] + p4.x] = rankOf[s4.x];
            srcs[rowptrP[d4.y] + p4.y] = rankOf[s4.y];
            srcs[rowptrP[d4.z] + p4.z] = rankOf[s4.z];
            srcs[rowptrP[d4.w] + p4.w] = rankOf[s4.w];
        } else {
            for (int e = e0; e < E; e++)
                srcs[rowptrP[ei[E + e]] + pidx[e]] = rankOf[ei[e]];
        }
    } else {
        __shared__ int pS[16];
        __shared__ float dS[16];
        const int base = (b - fillBlocks) * 16;
        const int t = threadIdx.x;
        if (t == 0 && base == 0) {
            int4 sv; sv.x = sv.y = sv.z = sv.w = 0; *(int4*)sentIdx = sv;  // zero slot
        }
        if (t < 16) {
            const int r = base + t;
            int p = -1; float dv = 0.f;
            if (r >= 1 && r <= N) {
                p = perm[r];
                rbegR[r] = rowptrP[p];
                rpenR[r] = rowptrP[p + 1];    // padded end (next padded start)
                dv = dinv[p];
                dinvR[r] = dv;
            } else if (r < NS) {
                rbegR[r] = 0; rpenR[r] = 0; dinvR[r] = 0.f;
            }
            pS[t] = p; dS[t] = dv;
        }
        __syncthreads();
        const int rr = base + (t >> 4);
        if (rr >= NS) return;
        const int j = t & 15;
        const int p = pS[t >> 4];
        if (p >= 0) {
            const float s = dS[t >> 4];
            const float4 v0 = *(const float4*)(x + (size_t)p * D + j * 8);
            const float4 v1 = *(const float4*)(x + (size_t)p * D + j * 8 + 4);
            half8 h;
            h[0] = (_Float16)(v0.x * s); h[1] = (_Float16)(v0.y * s);
            h[2] = (_Float16)(v0.z * s); h[3] = (_Float16)(v0.w * s);
            h[4] = (_Float16)(v1.x * s); h[5] = (_Float16)(v1.y * s);
            h[6] = (_Float16)(v1.z * s); h[7] = (_Float16)(v1.w * s);
            *(half8*)(gA + (size_t)rr * D + j * 8) = h;
        } else {
            half8 z;
#pragma unroll
            for (int j2 = 0; j2 < 8; j2++) z[j2] = (_Float16)0.f;
            *(half8*)(gA + (size_t)rr * D + j * 8) = z;
            *(half8*)(gB + (size_t)rr * D + j * 8) = z;
        }
    }
}

// ============ fused layer: gout = scale ⊙ relu( (dinv ⊙ Â g) @ W + b ) ============
// FROZEN at R6 structure (8 nodes/wave, 32/block, backfill occupancy ~60%):
// measured at the random-gather EA service wall (~2.7 TB/s, concurrency-
// insensitive per R3/R5/R6 A/B). Sentinel slot is now 0 (zero row).

__global__ __launch_bounds__(256, 8) void k_layer(
        const _Float16* __restrict__ gin,
        const int* __restrict__ rbegR, const int* __restrict__ rpenR,
        const int* __restrict__ srcs,
        const int* __restrict__ sentIdx,
        const float* __restrict__ dinvR,
        const int* __restrict__ perm,
        const _Float16* __restrict__ Wf,
        const float* __restrict__ bias,
        _Float16* __restrict__ gout, int N, int last) {
    __shared__ _Float16 S[32 * LSTRIDE];   // 8.7 KB

    const int tid  = threadIdx.x;
    const int w    = tid >> 6;        // wave 0..3
    const int lane = tid & 63;
    const int q    = lane >> 4;       // group 0..3
    const int l16  = lane & 15;       // lane-in-group; col base = l16*8
    const int sb   = blockIdx.x * 32; // slot base
    const int cb   = l16 * 8;
    const int slot0 = sb + w * 8 + q * 2;

    // ---- phase 1: branch-free interleaved gather over the group's 2 slots ----
    int bg[2], nc[2];
    int mx = 0;
#pragma unroll
    for (int it = 0; it < 2; it++) {
        bg[it] = rbegR[slot0 + it];
        nc[it] = (rpenR[slot0 + it] - bg[it]) >> 2;   // padded chunk count
        mx = nc[it] > mx ? nc[it] : mx;
    }

    float a[2][8];
#pragma unroll
    for (int it = 0; it < 2; it++) {                  // self-loop rows (coalesced)
        half8 sv = *(const half8*)(gin + (size_t)(slot0 + it) * D + cb);
#pragma unroll
        for (int j = 0; j < 8; j++) a[it][j] = (float)sv[j];
    }

    int4 cur[2];
#pragma unroll
    for (int it = 0; it < 2; it++) {
        const int* ip = (0 < nc[it]) ? (srcs + bg[it]) : sentIdx;
        cur[it] = *(const int4*)ip;
    }
    for (int ch = 0; ch < mx; ch++) {
        int4 nxt[2];
#pragma unroll
        for (int it = 0; it < 2; it++) {              // prefetch next chunk's indices
            const int* ip = (ch + 1 < nc[it]) ? (srcs + bg[it] + (ch + 1) * 4) : sentIdx;
            nxt[it] = *(const int4*)ip;
        }
#pragma unroll
        for (int it = 0; it < 2; it++) {              // 8 row loads in flight
            half8 v0 = *(const half8*)(gin + (size_t)cur[it].x * D + cb);
            half8 v1 = *(const half8*)(gin + (size_t)cur[it].y * D + cb);
            half8 v2 = *(const half8*)(gin + (size_t)cur[it].z * D + cb);
            half8 v3 = *(const half8*)(gin + (size_t)cur[it].w * D + cb);
#pragma unroll
            for (int j = 0; j < 8; j++)
                a[it][j] += ((float)v0[j] + (float)v1[j]) + ((float)v2[j] + (float)v3[j]);
        }
#pragma unroll
        for (int it = 0; it < 2; it++) cur[it] = nxt[it];
    }

#pragma unroll
    for (int it = 0; it < 2; it++) {
        const float sc = dinvR[slot0 + it];
        const int nl = w * 8 + q * 2 + it;
        half8 o;
#pragma unroll
        for (int j = 0; j < 8; j++) o[j] = (_Float16)(a[it][j] * sc);
        *(half8*)(&S[nl * LSTRIDE + cb]) = o;
    }

    __syncthreads();   // cross-wave: wave pair reads each other's S rows

    // ---- phase 2: S @ W via MFMA; wave pair splits the 8 cc's of one tile ----
    f32x4 acc[4];
#pragma unroll
    for (int c2 = 0; c2 < 4; c2++) acc[c2] = (f32x4){0.f, 0.f, 0.f, 0.f};

    const int tile = w >> 1;               // 0..1: which 16-node tile
    const int ccb  = (w & 1) * 4;          // this wave's cc range
    const int nl2  = tile * 16 + l16;      // this lane's slot row (B-frag)
#pragma unroll
    for (int s = 0; s < 4; s++) {
        half8 bf = *(const half8*)(&S[nl2 * LSTRIDE + s * 32 + q * 8]);
#pragma unroll
        for (int c2 = 0; c2 < 4; c2++) {
            half8 wh = *(const half8*)(Wf + (size_t)((s * 8 + ccb + c2) * 64 + lane) * 8);
            acc[c2] = __builtin_amdgcn_mfma_f32_16x16x32_f16(wh, bf, acc[c2], 0, 0, 0);
        }
    }

    // epilogue: D[m = W-col = q*4+r][n = slot = l16]
    const int slot2 = sb + nl2;
    if (!last) {
        const float scale = dinvR[slot2];             // 0 for dummy slots -> stays 0
        _Float16* rp = gout + (size_t)slot2 * D + q * 4;
#pragma unroll
        for (int c2 = 0; c2 < 4; c2++) {
            const int cc = ccb + c2;
            const float4 bc = *(const float4*)(bias + cc * 16 + q * 4);
            half4v o;
            o[0] = (_Float16)(fmaxf(acc[c2][0] + bc.x, 0.f) * scale);
            o[1] = (_Float16)(fmaxf(acc[c2][1] + bc.y, 0.f) * scale);
            o[2] = (_Float16)(fmaxf(acc[c2][2] + bc.z, 0.f) * scale);
            o[3] = (_Float16)(fmaxf(acc[c2][3] + bc.w, 0.f) * scale);
            *(half4v*)(rp + cc * 16) = o;   // 8 B store, coalesced rows
        }
    } else if (slot2 >= 1 && slot2 <= N) {
        const int node2 = perm[slot2];                // back to original order
        _Float16* rp = gout + (size_t)node2 * D + q * 4;
#pragma unroll
        for (int c2 = 0; c2 < 4; c2++) {
            const int cc = ccb + c2;
            const float4 bc = *(const float4*)(bias + cc * 16 + q * 4);
            half4v o;
            o[0] = (_Float16)fmaxf(acc[c2][0] + bc.x, 0.f);
            o[1] = (_Float16)fmaxf(acc[c2][1] + bc.y, 0.f);
            o[2] = (_Float16)fmaxf(acc[c2][2] + bc.z, 0.f);
            o[3] = (_Float16)fmaxf(acc[c2][3] + bc.w, 0.f);
            *(half4v*)(rp + cc * 16) = o;
        }
    }
}

// ========== fused pool + MLP head: one block (256 thr) per graph ==========

__global__ __launch_bounds__(256) void k_poolhead(
        const _Float16* __restrict__ h, const int* __restrict__ batch,
        const float* __restrict__ W1, const float* __restrict__ b1,
        const float* __restrict__ W2, const float* __restrict__ b2,
        const float* __restrict__ W3, const float* __restrict__ b3,
        float* __restrict__ out, int N) {
    __shared__ int sb[2];
    __shared__ float part[16][D];
    __shared__ float pool[D];
    __shared__ float z[D];
    __shared__ float red[D];
    __shared__ float pr[2][D];

    const int g = blockIdx.x;
    const int t = threadIdx.x;

    if (t < 2) {
        int target = g + t;
        int lo = 0, hi = N;
        while (lo < hi) {
            int mid = (lo + hi) >> 1;
            if (batch[mid] < target) lo = mid + 1; else hi = mid;
        }
        sb[t] = lo;
    }
    __syncthreads();
    const int rs = sb[0], re = sb[1];

    const int w = t >> 6;
    const int lane = t & 63;
    const int rw = w * 4 + (lane >> 4);   // 0..15: row-slot within the 16-row stride
    const int c8 = (lane & 15) * 8;

    float ax[8];
#pragma unroll
    for (int j = 0; j < 8; j++) ax[j] = 0.f;
    for (int r = rs + rw; r < re; r += 16) {
        half8 vv = *(const half8*)(h + (size_t)r * D + c8);
#pragma unroll
        for (int j = 0; j < 8; j++) ax[j] += (float)vv[j];
    }
#pragma unroll
    for (int j = 0; j < 8; j++) part[rw][c8 + j] = ax[j];
    __syncthreads();

    if (t < D) {
        float s = 0.f;
#pragma unroll
        for (int gg = 0; gg < 16; gg++) s += part[gg][t];
        pool[t] = s;
    }
    __syncthreads();

    // matvec1: k-split across the two block halves, LDS combine
    {
        const int hf = t >> 7, tt = t & 127;
        const int k0 = hf * 64;
        float s = 0.f;
        for (int k = k0; k < k0 + 64; k++) s = fmaf(pool[k], W1[(size_t)k * D + tt], s);
        pr[hf][tt] = s;
    }
    __syncthreads();
    if (t < D) z[t] = fmaxf(pr[0][t] + pr[1][t] + b1[t], 0.f);
    __syncthreads();

    // matvec2: same split
    {
        const int hf = t >> 7, tt = t & 127;
        const int k0 = hf * 64;
        float s = 0.f;
        for (int k = k0; k < k0 + 64; k++) s = fmaf(z[k], W2[(size_t)k * D + tt], s);
        pr[hf][tt] = s;
    }
    __syncthreads();
    if (t < D) red[t] = fmaxf(pr[0][t] + pr[1][t] + b2[t], 0.f) * W3[t];
    __syncthreads();
    for (int off = 64; off >= 1; off >>= 1) {
        if (t < off) red[t] += red[t + off];
        __syncthreads();
    }
    if (t == 0) out[g] = 1.f / (1.f + expf(-(red[0] + b3[0])));
}

// ================= orchestration =================

extern "C" void kernel_launch(void* const* d_in, const int* in_sizes, int n_in,
                              void* d_out, int out_size, void* d_ws, size_t ws_size,
                              hipStream_t stream) {
    const float* x     = (const float*)d_in[0];
    const int*   ei    = (const int*)d_in[1];
    const int*   batch = (const int*)d_in[2];
    const float* convW = (const float*)d_in[3];
    const float* convB = (const float*)d_in[4];
    const float* W1 = (const float*)d_in[5];
    const float* b1 = (const float*)d_in[6];
    const float* W2 = (const float*)d_in[7];
    const float* b2 = (const float*)d_in[8];
    const float* W3 = (const float*)d_in[9];
    const float* b3 = (const float*)d_in[10];
    float* out = (float*)d_out;

    const int N = in_sizes[0] / D;          // 100000
    const int E = in_sizes[1] / 2;          // 640000
    const int G = out_size;                 // 512
    const int NB = (N + 1023) / 1024;
    const int NS = ((N + 1 + 63) / 64) * 64;  // slots: 0 = zero/sentinel row, 1..N real

    // ---- workspace layout ----
    char* w = (char*)d_ws;
    size_t off = 0;
    auto alloc = [&](size_t bytes) -> char* {
        char* p = w + off;
        off += (bytes + 255) & ~(size_t)255;
        return p;
    };
    float*     dinv   = (float*)alloc((size_t)N * 4);
    _Float16*  gA     = (_Float16*)alloc((size_t)NS * D * 2);
    _Float16*  gB     = (_Float16*)alloc((size_t)NS * D * 2);
    _Float16*  Wf     = (_Float16*)alloc((size_t)4 * D * D * 2);
    int*       counts = (int*)alloc((size_t)(N + 128) * 4);  // + degHist[64] + degCur[64]
    int*       degHist= counts + N;
    int*       degCur = counts + N + 64;
    int*       rowptrP= (int*)alloc((size_t)(N + 1) * 4);
    int*       pidx   = (int*)alloc((size_t)E * 4);
    int*       srcs   = (int*)alloc((size_t)(E + 3 * N) * 4);
    int*       bsums  = (int*)alloc((size_t)NB * 4);
    int*       perm   = (int*)alloc((size_t)(N + 1) * 4);
    int*       rankOf = (int*)alloc((size_t)N * 4);
    int*       rbegR  = (int*)alloc((size_t)NS * 4);
    int*       rpenR  = (int*)alloc((size_t)NS * 4);
    float*     dinvR  = (float*)alloc((size_t)NS * 4);
    int*       sentIdx= (int*)alloc(16);

    // ---- CSR build + sort + rank-space tables + cvt ----
    hipMemsetAsync(counts, 0, (size_t)(N + 128) * 4, stream);
    hipMemsetAsync(srcs, 0, (size_t)(E + 3 * N) * 4, stream);   // pads -> sentinel 0
    const int countBlocks = (E / 4 + 255) / 256;
    k_fat1<<<countBlocks + 32, 256, 0, stream>>>(ei, counts, pidx, E, countBlocks,
                                                 convW, Wf);
    k_scan1<<<NB, 256, 0, stream>>>(counts, rowptrP, bsums, dinv, degHist, N);
    const int scanBlocks = (N + 1 + 255) / 256;
    const int rankBlocks = (N + 255) / 256;
    k_fat2<<<scanBlocks + rankBlocks, 256, 0, stream>>>(rowptrP, counts, bsums, NB, N,
                                                        scanBlocks,
                                                        degHist, degCur, perm, rankOf);
    const int fillBlocks = (E / 4 + 255) / 256;
    const int rowBlocks  = NS / 16;          // slots 0..NS-1
    k_fill<<<fillBlocks + rowBlocks, 256, 0, stream>>>(
        ei, rowptrP, pidx, srcs, E, fillBlocks, N, NS,
        rankOf, perm, dinv, rbegR, rpenR, dinvR, sentIdx, x, gA, gB);

    // ---- 4 fused GCN layers (ping-pong, rank space; last scatters to orig) ----
    const int layer_grid = NS / 32;
    const _Float16* gi = gA;
    _Float16* go = gB;
    for (int l = 0; l < 4; l++) {
        k_layer<<<layer_grid, 256, 0, stream>>>(gi, rbegR, rpenR, srcs, sentIdx,
                                                dinvR, perm,
                                                Wf + (size_t)l * D * D,
                                                convB + (size_t)l * D,
                                                go, N, l == 3);
        const _Float16* tmp = go;
        go = (_Float16*)gi;
        gi = tmp;
    }

    // ---- fused pool + head ----
    k_poolhead<<<G, 256, 0, stream>>>(gi, batch, W1, b1, W2, b2, W3, b3, out, N);
}

// Round 10
// 333.086 us; speedup vs baseline: 1.0842x; 1.0317x over previous
//
#include <hip/hip_runtime.h>
#include <math.h>

#define D 128
#define LSTRIDE 136   // LDS row stride in halves

typedef _Float16 half8 __attribute__((ext_vector_type(8)));
typedef _Float16 half4v __attribute__((ext_vector_type(4)));
typedef float f32x4 __attribute__((ext_vector_type(4)));

// ============ pass 1: bucket histogram (dst>>8) + weight pre-pack ============
// 4096 edges/block; LDS bins then one global add per touched bin per block.

__global__ __launch_bounds__(256) void k_bhist(const int* __restrict__ ei, int E,
                                               int edgeBlocks, int NBUK,
                                               int* __restrict__ bukCnt,
                                               const float* __restrict__ convW,
                                               _Float16* __restrict__ Wf) {
    if ((int)blockIdx.x < edgeBlocks) {
        __shared__ int lh[512];
        const int t = threadIdx.x;
        for (int i = t; i < NBUK; i += 256) lh[i] = 0;
        __syncthreads();
        const int base = blockIdx.x * 4096;
#pragma unroll
        for (int k = 0; k < 4; k++) {
            const int e0 = base + k * 1024 + t * 4;
            if (e0 + 3 < E) {
                int4 d4 = *(const int4*)(ei + E + e0);
                atomicAdd(&lh[d4.x >> 8], 1);
                atomicAdd(&lh[d4.y >> 8], 1);
                atomicAdd(&lh[d4.z >> 8], 1);
                atomicAdd(&lh[d4.w >> 8], 1);
            } else {
                for (int e = e0; e < E && e < e0 + 4; e++)
                    atomicAdd(&lh[ei[E + e] >> 8], 1);
            }
        }
        __syncthreads();
        for (int i = t; i < NBUK; i += 256)
            if (lh[i]) atomicAdd(&bukCnt[i], lh[i]);
    } else {
        // prepw: slot = (s*8+c)*64 + lane; elem j: k = s*32+(lane>>4)*8+j, n = c*16+(lane&15)
        const int bid = blockIdx.x - edgeBlocks;            // 0..31
        const int l = bid >> 3;                             // layer
        const int slot = (bid & 7) * 256 + threadIdx.x;
        const float* W = convW + (size_t)l * D * D;
        const int p = slot >> 6, ln = slot & 63;
        const int s = p >> 3, c = p & 7;
        const int kbase = s * 32 + ((ln >> 4) << 3);
        const int n = (c << 4) + (ln & 15);
        half8 hv;
#pragma unroll
        for (int j = 0; j < 8; j++) hv[j] = (_Float16)W[(size_t)(kbase + j) * D + n];
        *(half8*)(Wf + (size_t)l * D * D + (size_t)slot * 8) = hv;
    }
}

// ============ pass 2: scan bucket counts -> bukPtr (excl) / bukCur ============

__global__ __launch_bounds__(512) void k_bscan(const int* __restrict__ bukCnt,
                                               int* __restrict__ bukPtr,
                                               int* __restrict__ bukCur, int NBUK) {
    __shared__ int sh[512];
    const int t = threadIdx.x;
    sh[t] = (t < NBUK) ? bukCnt[t] : 0;
    __syncthreads();
    for (int off = 1; off < 512; off <<= 1) {
        int v = (t >= off) ? sh[t - off] : 0;
        __syncthreads();
        sh[t] += v;
        __syncthreads();
    }
    if (t < NBUK) {
        int excl = (t == 0) ? 0 : sh[t - 1];
        bukPtr[t] = excl;
        bukCur[t] = excl;
    }
    if (t == NBUK) bukPtr[t] = sh[NBUK - 1];
    else if (NBUK < 512 && t == 511 && NBUK == 512) {}   // (unreachable; NBUK<512)
}

// ============ pass 3: partition edges into bucket-ordered ebuk[] ============
// LDS local ranks + one returning global atomic per (block,bucket).

__global__ __launch_bounds__(256) void k_bscat(const int* __restrict__ ei, int E,
                                               int NBUK, int* __restrict__ bukCur,
                                               int2* __restrict__ ebuk) {
    __shared__ int lcnt[512];
    __shared__ int lbase[512];
    const int t = threadIdx.x;
    for (int i = t; i < NBUK; i += 256) lcnt[i] = 0;
    __syncthreads();
    const int base = blockIdx.x * 4096;
    int es[16], ed[16], lr[16];
#pragma unroll
    for (int k = 0; k < 4; k++) {
        const int e0 = base + k * 1024 + t * 4;
        if (e0 + 3 < E) {
            int4 s4 = *(const int4*)(ei + e0);
            int4 d4 = *(const int4*)(ei + E + e0);
            es[k * 4 + 0] = s4.x; ed[k * 4 + 0] = d4.x;
            es[k * 4 + 1] = s4.y; ed[k * 4 + 1] = d4.y;
            es[k * 4 + 2] = s4.z; ed[k * 4 + 2] = d4.z;
            es[k * 4 + 3] = s4.w; ed[k * 4 + 3] = d4.w;
        } else {
#pragma unroll
            for (int j = 0; j < 4; j++) {
                const int e = e0 + j;
                if (e < E) { es[k * 4 + j] = ei[e]; ed[k * 4 + j] = ei[E + e]; }
                else ed[k * 4 + j] = -1;
            }
        }
    }
#pragma unroll
    for (int i = 0; i < 16; i++)
        if (ed[i] >= 0) lr[i] = atomicAdd(&lcnt[ed[i] >> 8], 1);
    __syncthreads();
    for (int i = t; i < NBUK; i += 256)
        lbase[i] = lcnt[i] ? atomicAdd(&bukCur[i], lcnt[i]) : 0;
    __syncthreads();
#pragma unroll
    for (int i = 0; i < 16; i++) {
        if (ed[i] >= 0) {
            int2 e2; e2.x = es[i]; e2.y = ed[i];
            ebuk[lbase[ed[i] >> 8] + lr[i]] = e2;
        }
    }
}

// ============ pass 4: per-bucket degree count (LDS atomics, no global) ============

__global__ __launch_bounds__(256) void k_bcount(const int2* __restrict__ ebuk,
                                                const int* __restrict__ bukPtr,
                                                int* __restrict__ counts, int N) {
    __shared__ int cnt[256];
    const int b = blockIdx.x, t = threadIdx.x;
    cnt[t] = 0;
    __syncthreads();
    const int beg = bukPtr[b], end = bukPtr[b + 1];
    for (int i = beg + t; i < end; i += 256) {
        int2 e = ebuk[i];
        atomicAdd(&cnt[e.y & 255], 1);
    }
    __syncthreads();
    const int node = b * 256 + t;
    if (node < N) counts[node] = cnt[t];
}

// scan over PADDED counts (ceil4) -> rowptrP (16B-aligned row starts);
// emits dinv = rsqrt(count+1) and a 64-bin degree histogram.
__global__ __launch_bounds__(256) void k_scan1(const int* __restrict__ counts,
                                               int* __restrict__ rowptrP,
                                               int* __restrict__ bsums,
                                               float* __restrict__ dinv,
                                               int* __restrict__ degHist, int N) {
    __shared__ int sh[256];
    __shared__ int lh[64];
    const int t = threadIdx.x;
    const int base = blockIdx.x * 1024 + t * 4;
    int c[4], pj[4];
#pragma unroll
    for (int j = 0; j < 4; j++) {
        c[j] = (base + j < N) ? counts[base + j] : 0;
        pj[j] = (c[j] + 3) & ~3;
    }
#pragma unroll
    for (int j = 0; j < 4; j++)
        if (base + j < N) dinv[base + j] = rsqrtf((float)(c[j] + 1));

    if (t < 64) lh[t] = 0;
    __syncthreads();
#pragma unroll
    for (int j = 0; j < 4; j++)
        if (base + j < N) atomicAdd(&lh[c[j] < 63 ? c[j] : 63], 1);
    __syncthreads();
    if (t < 64 && lh[t]) atomicAdd(&degHist[t], lh[t]);

    int tsum = pj[0] + pj[1] + pj[2] + pj[3];
    sh[t] = tsum;
    __syncthreads();
    for (int off = 1; off < 256; off <<= 1) {
        int v = (t >= off) ? sh[t - off] : 0;
        __syncthreads();
        sh[t] += v;
        __syncthreads();
    }
    int run = (t == 0) ? 0 : sh[t - 1];
    if (t == 255) bsums[blockIdx.x] = sh[255];
#pragma unroll
    for (int j = 0; j < 4; j++) {
        if (base + j <= N) rowptrP[base + j] = run;
        run += pj[j];
    }
}

// ============ fat2: scan3 (block prefix; srcs pre-memset to 0, sentinel slot 0)
//              + counting-sort (ranks 1..N desc by degree; slot 0 = zero row) ====

__global__ __launch_bounds__(256) void k_fat2(int* __restrict__ rowptrP,
                                              const int* __restrict__ counts,
                                              const int* __restrict__ bsums,
                                              int NB, int N, int scanBlocks,
                                              const int* __restrict__ degHist,
                                              int* __restrict__ degCur,
                                              int* __restrict__ perm,
                                              int* __restrict__ rankOf) {
    if ((int)blockIdx.x < scanBlocks) {
        __shared__ int pre[128];
        const int t = threadIdx.x;
        if (t < 128) pre[t] = (t < NB) ? bsums[t] : 0;
        __syncthreads();
        for (int off = 1; off < 128; off <<= 1) {
            int v = (t >= off && t < 128) ? pre[t - off] : 0;
            __syncthreads();
            if (t < 128) pre[t] += v;
            __syncthreads();
        }
        int i = blockIdx.x * blockDim.x + t;
        if (i <= N) {
            int b = i >> 10;
            int add = (b == 0) ? 0 : pre[b - 1];
            rowptrP[i] += add;
        }
    } else {
        __shared__ int lbase[64], lh[64], gb[64];
        const int t = threadIdx.x;
        const int i = ((int)blockIdx.x - scanBlocks) * blockDim.x + t;
        if (t < 64) lh[t] = 0;
        __syncthreads();
        int deg = 0, lrank = 0;
        const bool v = i < N;
        if (v) {
            int c = counts[i];
            deg = c < 63 ? c : 63;
            lrank = atomicAdd(&lh[deg], 1);
        }
        __syncthreads();
        if (t < 64) gb[t] = lh[t] ? atomicAdd(&degCur[t], lh[t]) : 0;
        if (t == 0) {
            int run = 0;
            for (int d = 63; d >= 0; d--) { lbase[d] = run; run += degHist[d]; }
        }
        __syncthreads();
        if (v) {
            int r = 1 + lbase[deg] + gb[deg] + lrank;   // slots 1..N
            perm[r] = i;
            rankOf[i] = r;
        }
    }
}

// ============ pass 7: per-bucket CSR fill (LDS cursors) + slot tables + cvt ============

__global__ void k_bfill(const int2* __restrict__ ebuk, const int* __restrict__ bukPtr,
                        const int* __restrict__ rowptrP, int* __restrict__ srcs,
                        const int* __restrict__ rankOf, int NBUK, int N, int NS,
                        const int* __restrict__ perm,
                        const float* __restrict__ dinv,
                        int* __restrict__ rbegR, int* __restrict__ rpenR,
                        float* __restrict__ dinvR, int* __restrict__ sentIdx,
                        const float* __restrict__ x,
                        _Float16* __restrict__ gA, _Float16* __restrict__ gB) {
    const int b = blockIdx.x;
    if (b < NBUK) {
        __shared__ int cur[256];
        const int t = threadIdx.x;
        const int node = b * 256 + t;
        cur[t] = (node < N) ? rowptrP[node] : 0;
        __syncthreads();
        const int beg = bukPtr[b], end = bukPtr[b + 1];
        for (int i = beg + t; i < end; i += 256) {
            int2 e = ebuk[i];
            int p = atomicAdd(&cur[e.y & 255], 1);    // LDS atomic
            srcs[p] = rankOf[e.x];
        }
    } else {
        __shared__ int pS[16];
        __shared__ float dS[16];
        const int base = (b - NBUK) * 16;
        const int t = threadIdx.x;
        if (t == 0 && base == 0) {
            int4 sv; sv.x = sv.y = sv.z = sv.w = 0; *(int4*)sentIdx = sv;  // zero slot
        }
        if (t < 16) {
            const int r = base + t;
            int p = -1; float dv = 0.f;
            if (r >= 1 && r <= N) {
                p = perm[r];
                rbegR[r] = rowptrP[p];
                rpenR[r] = rowptrP[p + 1];    // padded end (next padded start)
                dv = dinv[p];
                dinvR[r] = dv;
            } else if (r < NS) {
                rbegR[r] = 0; rpenR[r] = 0; dinvR[r] = 0.f;
            }
            pS[t] = p; dS[t] = dv;
        }
        __syncthreads();
        const int rr = base + (t >> 4);
        if (rr >= NS) return;
        const int j = t & 15;
        const int p = pS[t >> 4];
        if (p >= 0) {
            const float s = dS[t >> 4];
            const float4 v0 = *(const float4*)(x + (size_t)p * D + j * 8);
            const float4 v1 = *(const float4*)(x + (size_t)p * D + j * 8 + 4);
            half8 h;
            h[0] = (_Float16)(v0.x * s); h[1] = (_Float16)(v0.y * s);
            h[2] = (_Float16)(v0.z * s); h[3] = (_Float16)(v0.w * s);
            h[4] = (_Float16)(v1.x * s); h[5] = (_Float16)(v1.y * s);
            h[6] = (_Float16)(v1.z * s); h[7] = (_Float16)(v1.w * s);
            *(half8*)(gA + (size_t)rr * D + j * 8) = h;
        } else {
            half8 z;
#pragma unroll
            for (int j2 = 0; j2 < 8; j2++) z[j2] = (_Float16)0.f;
            *(half8*)(gA + (size_t)rr * D + j * 8) = z;
            *(half8*)(gB + (size_t)rr * D + j * 8) = z;
        }
    }
}

// ============ fused layer: gout = scale ⊙ relu( (dinv ⊙ Â g) @ W + b ) ============
// FROZEN at R6 structure (8 nodes/wave, 32/block, backfill occupancy ~60%):
// measured at the random-gather EA service wall (~2.7 TB/s, concurrency-
// insensitive per R3/R5/R6 A/B). Sentinel slot = 0 (zero row).

__global__ __launch_bounds__(256, 8) void k_layer(
        const _Float16* __restrict__ gin,
        const int* __restrict__ rbegR, const int* __restrict__ rpenR,
        const int* __restrict__ srcs,
        const int* __restrict__ sentIdx,
        const float* __restrict__ dinvR,
        const int* __restrict__ perm,
        const _Float16* __restrict__ Wf,
        const float* __restrict__ bias,
        _Float16* __restrict__ gout, int N, int last) {
    __shared__ _Float16 S[32 * LSTRIDE];   // 8.7 KB

    const int tid  = threadIdx.x;
    const int w    = tid >> 6;        // wave 0..3
    const int lane = tid & 63;
    const int q    = lane >> 4;       // group 0..3
    const int l16  = lane & 15;       // lane-in-group; col base = l16*8
    const int sb   = blockIdx.x * 32; // slot base
    const int cb   = l16 * 8;
    const int slot0 = sb + w * 8 + q * 2;

    // ---- phase 1: branch-free interleaved gather over the group's 2 slots ----
    int bg[2], nc[2];
    int mx = 0;
#pragma unroll
    for (int it = 0; it < 2; it++) {
        bg[it] = rbegR[slot0 + it];
        nc[it] = (rpenR[slot0 + it] - bg[it]) >> 2;   // padded chunk count
        mx = nc[it] > mx ? nc[it] : mx;
    }

    float a[2][8];
#pragma unroll
    for (int it = 0; it < 2; it++) {                  // self-loop rows (coalesced)
        half8 sv = *(const half8*)(gin + (size_t)(slot0 + it) * D + cb);
#pragma unroll
        for (int j = 0; j < 8; j++) a[it][j] = (float)sv[j];
    }

    int4 cur[2];
#pragma unroll
    for (int it = 0; it < 2; it++) {
        const int* ip = (0 < nc[it]) ? (srcs + bg[it]) : sentIdx;
        cur[it] = *(const int4*)ip;
    }
    for (int ch = 0; ch < mx; ch++) {
        int4 nxt[2];
#pragma unroll
        for (int it = 0; it < 2; it++) {              // prefetch next chunk's indices
            const int* ip = (ch + 1 < nc[it]) ? (srcs + bg[it] + (ch + 1) * 4) : sentIdx;
            nxt[it] = *(const int4*)ip;
        }
#pragma unroll
        for (int it = 0; it < 2; it++) {              // 8 row loads in flight
            half8 v0 = *(const half8*)(gin + (size_t)cur[it].x * D + cb);
            half8 v1 = *(const half8*)(gin + (size_t)cur[it].y * D + cb);
            half8 v2 = *(const half8*)(gin + (size_t)cur[it].z * D + cb);
            half8 v3 = *(const half8*)(gin + (size_t)cur[it].w * D + cb);
#pragma unroll
            for (int j = 0; j < 8; j++)
                a[it][j] += ((float)v0[j] + (float)v1[j]) + ((float)v2[j] + (float)v3[j]);
        }
#pragma unroll
        for (int it = 0; it < 2; it++) cur[it] = nxt[it];
    }

#pragma unroll
    for (int it = 0; it < 2; it++) {
        const float sc = dinvR[slot0 + it];
        const int nl = w * 8 + q * 2 + it;
        half8 o;
#pragma unroll
        for (int j = 0; j < 8; j++) o[j] = (_Float16)(a[it][j] * sc);
        *(half8*)(&S[nl * LSTRIDE + cb]) = o;
    }

    __syncthreads();   // cross-wave: wave pair reads each other's S rows

    // ---- phase 2: S @ W via MFMA; wave pair splits the 8 cc's of one tile ----
    f32x4 acc[4];
#pragma unroll
    for (int c2 = 0; c2 < 4; c2++) acc[c2] = (f32x4){0.f, 0.f, 0.f, 0.f};

    const int tile = w >> 1;               // 0..1: which 16-node tile
    const int ccb  = (w & 1) * 4;          // this wave's cc range
    const int nl2  = tile * 16 + l16;      // this lane's slot row (B-frag)
#pragma unroll
    for (int s = 0; s < 4; s++) {
        half8 bf = *(const half8*)(&S[nl2 * LSTRIDE + s * 32 + q * 8]);
#pragma unroll
        for (int c2 = 0; c2 < 4; c2++) {
            half8 wh = *(const half8*)(Wf + (size_t)((s * 8 + ccb + c2) * 64 + lane) * 8);
            acc[c2] = __builtin_amdgcn_mfma_f32_16x16x32_f16(wh, bf, acc[c2], 0, 0, 0);
        }
    }

    // epilogue: D[m = W-col = q*4+r][n = slot = l16]
    const int slot2 = sb + nl2;
    if (!last) {
        const float scale = dinvR[slot2];             // 0 for dummy slots -> stays 0
        _Float16* rp = gout + (size_t)slot2 * D + q * 4;
#pragma unroll
        for (int c2 = 0; c2 < 4; c2++) {
            const int cc = ccb + c2;
            const float4 bc = *(const float4*)(bias + cc * 16 + q * 4);
            half4v o;
            o[0] = (_Float16)(fmaxf(acc[c2][0] + bc.x, 0.f) * scale);
            o[1] = (_Float16)(fmaxf(acc[c2][1] + bc.y, 0.f) * scale);
            o[2] = (_Float16)(fmaxf(acc[c2][2] + bc.z, 0.f) * scale);
            o[3] = (_Float16)(fmaxf(acc[c2][3] + bc.w, 0.f) * scale);
            *(half4v*)(rp + cc * 16) = o;   // 8 B store, coalesced rows
        }
    } else if (slot2 >= 1 && slot2 <= N) {
        const int node2 = perm[slot2];                // back to original order
        _Float16* rp = gout + (size_t)node2 * D + q * 4;
#pragma unroll
        for (int c2 = 0; c2 < 4; c2++) {
            const int cc = ccb + c2;
            const float4 bc = *(const float4*)(bias + cc * 16 + q * 4);
            half4v o;
            o[0] = (_Float16)fmaxf(acc[c2][0] + bc.x, 0.f);
            o[1] = (_Float16)fmaxf(acc[c2][1] + bc.y, 0.f);
            o[2] = (_Float16)fmaxf(acc[c2][2] + bc.z, 0.f);
            o[3] = (_Float16)fmaxf(acc[c2][3] + bc.w, 0.f);
            *(half4v*)(rp + cc * 16) = o;
        }
    }
}

// ========== fused pool + MLP head: one block (256 thr) per graph ==========

__global__ __launch_bounds__(256) void k_poolhead(
        const _Float16* __restrict__ h, const int* __restrict__ batch,
        const float* __restrict__ W1, const float* __restrict__ b1,
        const float* __restrict__ W2, const float* __restrict__ b2,
        const float* __restrict__ W3, const float* __restrict__ b3,
        float* __restrict__ out, int N) {
    __shared__ int sb[2];
    __shared__ float part[16][D];
    __shared__ float pool[D];
    __shared__ float z[D];
    __shared__ float red[D];
    __shared__ float pr[2][D];

    const int g = blockIdx.x;
    const int t = threadIdx.x;

    if (t < 2) {
        int target = g + t;
        int lo = 0, hi = N;
        while (lo < hi) {
            int mid = (lo + hi) >> 1;
            if (batch[mid] < target) lo = mid + 1; else hi = mid;
        }
        sb[t] = lo;
    }
    __syncthreads();
    const int rs = sb[0], re = sb[1];

    const int w = t >> 6;
    const int lane = t & 63;
    const int rw = w * 4 + (lane >> 4);   // 0..15: row-slot within the 16-row stride
    const int c8 = (lane & 15) * 8;

    float ax[8];
#pragma unroll
    for (int j = 0; j < 8; j++) ax[j] = 0.f;
    for (int r = rs + rw; r < re; r += 16) {
        half8 vv = *(const half8*)(h + (size_t)r * D + c8);
#pragma unroll
        for (int j = 0; j < 8; j++) ax[j] += (float)vv[j];
    }
#pragma unroll
    for (int j = 0; j < 8; j++) part[rw][c8 + j] = ax[j];
    __syncthreads();

    if (t < D) {
        float s = 0.f;
#pragma unroll
        for (int gg = 0; gg < 16; gg++) s += part[gg][t];
        pool[t] = s;
    }
    __syncthreads();

    // matvec1: k-split across the two block halves, LDS combine
    {
        const int hf = t >> 7, tt = t & 127;
        const int k0 = hf * 64;
        float s = 0.f;
        for (int k = k0; k < k0 + 64; k++) s = fmaf(pool[k], W1[(size_t)k * D + tt], s);
        pr[hf][tt] = s;
    }
    __syncthreads();
    if (t < D) z[t] = fmaxf(pr[0][t] + pr[1][t] + b1[t], 0.f);
    __syncthreads();

    // matvec2: same split
    {
        const int hf = t >> 7, tt = t & 127;
        const int k0 = hf * 64;
        float s = 0.f;
        for (int k = k0; k < k0 + 64; k++) s = fmaf(z[k], W2[(size_t)k * D + tt], s);
        pr[hf][tt] = s;
    }
    __syncthreads();
    if (t < D) red[t] = fmaxf(pr[0][t] + pr[1][t] + b2[t], 0.f) * W3[t];
    __syncthreads();
    for (int off = 64; off >= 1; off >>= 1) {
        if (t < off) red[t] += red[t + off];
        __syncthreads();
    }
    if (t == 0) out[g] = 1.f / (1.f + expf(-(red[0] + b3[0])));
}

// ================= orchestration =================

extern "C" void kernel_launch(void* const* d_in, const int* in_sizes, int n_in,
                              void* d_out, int out_size, void* d_ws, size_t ws_size,
                              hipStream_t stream) {
    const float* x     = (const float*)d_in[0];
    const int*   ei    = (const int*)d_in[1];
    const int*   batch = (const int*)d_in[2];
    const float* convW = (const float*)d_in[3];
    const float* convB = (const float*)d_in[4];
    const float* W1 = (const float*)d_in[5];
    const float* b1 = (const float*)d_in[6];
    const float* W2 = (const float*)d_in[7];
    const float* b2 = (const float*)d_in[8];
    const float* W3 = (const float*)d_in[9];
    const float* b3 = (const float*)d_in[10];
    float* out = (float*)d_out;

    const int N = in_sizes[0] / D;          // 100000
    const int E = in_sizes[1] / 2;          // 640000
    const int G = out_size;                 // 512
    const int NB = (N + 1023) / 1024;
    const int NS = ((N + 1 + 63) / 64) * 64;  // slots: 0 = zero/sentinel row, 1..N real
    const int NBUK = (N + 255) / 256;         // 391 buckets of 256 nodes

    // ---- workspace layout ----
    char* w = (char*)d_ws;
    size_t off = 0;
    auto alloc = [&](size_t bytes) -> char* {
        char* p = w + off;
        off += (bytes + 255) & ~(size_t)255;
        return p;
    };
    float*     dinv   = (float*)alloc((size_t)N * 4);
    _Float16*  gA     = (_Float16*)alloc((size_t)NS * D * 2);
    _Float16*  gB     = (_Float16*)alloc((size_t)NS * D * 2);
    _Float16*  Wf     = (_Float16*)alloc((size_t)4 * D * D * 2);
    int*       counts = (int*)alloc((size_t)N * 4);
    int*       misc   = (int*)alloc((size_t)(512 + 64 + 64) * 4);  // bukCnt|degHist|degCur
    int*       bukCnt = misc;
    int*       degHist= misc + 512;
    int*       degCur = misc + 576;
    int*       bukPtr = (int*)alloc((size_t)(NBUK + 1) * 4);
    int*       bukCur = (int*)alloc((size_t)NBUK * 4);
    int2*      ebuk   = (int2*)alloc((size_t)E * 8);
    int*       rowptrP= (int*)alloc((size_t)(N + 1) * 4);
    int*       srcs   = (int*)alloc((size_t)(E + 3 * N) * 4);
    int*       bsums  = (int*)alloc((size_t)NB * 4);
    int*       perm   = (int*)alloc((size_t)(N + 1) * 4);
    int*       rankOf = (int*)alloc((size_t)N * 4);
    int*       rbegR  = (int*)alloc((size_t)NS * 4);
    int*       rpenR  = (int*)alloc((size_t)NS * 4);
    float*     dinvR  = (float*)alloc((size_t)NS * 4);
    int*       sentIdx= (int*)alloc(16);

    // ---- CSR build (bucketed, no per-edge global atomics) + sort + tables + cvt ----
    hipMemsetAsync(misc, 0, (size_t)(512 + 64 + 64) * 4, stream);
    hipMemsetAsync(srcs, 0, (size_t)(E + 3 * N) * 4, stream);   // pads -> sentinel 0
    const int edgeBlocks = (E + 4095) / 4096;                   // 157
    k_bhist<<<edgeBlocks + 32, 256, 0, stream>>>(ei, E, edgeBlocks, NBUK, bukCnt,
                                                 convW, Wf);
    k_bscan<<<1, 512, 0, stream>>>(bukCnt, bukPtr, bukCur, NBUK);
    k_bscat<<<edgeBlocks, 256, 0, stream>>>(ei, E, NBUK, bukCur, ebuk);
    k_bcount<<<NBUK, 256, 0, stream>>>(ebuk, bukPtr, counts, N);
    k_scan1<<<NB, 256, 0, stream>>>(counts, rowptrP, bsums, dinv, degHist, N);
    const int scanBlocks = (N + 1 + 255) / 256;
    const int rankBlocks = (N + 255) / 256;
    k_fat2<<<scanBlocks + rankBlocks, 256, 0, stream>>>(rowptrP, counts, bsums, NB, N,
                                                        scanBlocks,
                                                        degHist, degCur, perm, rankOf);
    const int rowBlocks = NS / 16;          // slots 0..NS-1
    k_bfill<<<NBUK + rowBlocks, 256, 0, stream>>>(
        ebuk, bukPtr, rowptrP, srcs, rankOf, NBUK, N, NS,
        perm, dinv, rbegR, rpenR, dinvR, sentIdx, x, gA, gB);

    // ---- 4 fused GCN layers (ping-pong, rank space; last scatters to orig) ----
    const int layer_grid = NS / 32;
    const _Float16* gi = gA;
    _Float16* go = gB;
    for (int l = 0; l < 4; l++) {
        k_layer<<<layer_grid, 256, 0, stream>>>(gi, rbegR, rpenR, srcs, sentIdx,
                                                dinvR, perm,
                                                Wf + (size_t)l * D * D,
                                                convB + (size_t)l * D,
                                                go, N, l == 3);
        const _Float16* tmp = go;
        go = (_Float16*)gi;
        gi = tmp;
    }

    // ---- fused pool + head ----
    k_poolhead<<<G, 256, 0, stream>>>(gi, batch, W1, b1, W2, b2, W3, b3, out, N);
}